// Round 1
// baseline (652.311 us; speedup 1.0000x reference)
//
#include <hip/hip_runtime.h>
#include <hip/hip_bf16.h>

#define UF 512
#define EF 256
#define NB 64
#define NU 1024
#define NEN 1024

typedef __attribute__((ext_vector_type(8))) short short8;   // 8 bf16 (4 VGPRs)
typedef __attribute__((ext_vector_type(4))) float floatx4;  // MFMA acc

typedef unsigned short ushort_t;

__device__ inline short2 cvt2(float a, float b) {
    __hip_bfloat162 h = __float22bfloat162_rn(make_float2(a, b));
    union { __hip_bfloat162 h; short2 s; } u;
    u.h = h;
    return u.s;
}

__device__ inline short8 cvt8(float4 x, float4 y) {
    union { short8 v; short2 s[4]; } u;
    u.s[0] = cvt2(x.x, x.y);
    u.s[1] = cvt2(x.z, x.w);
    u.s[2] = cvt2(y.x, y.y);
    u.s[3] = cvt2(y.z, y.w);
    return u.v;
}

__device__ inline ushort_t f2bfbits(float f) {
    unsigned u = __float_as_uint(f);
    u += 0x7FFFu + ((u >> 16) & 1u);   // round-to-nearest-even
    return (ushort_t)(u >> 16);
}

// ---------------- K1: ||v||^2 ----------------
__global__ void knorm(const float* __restrict__ v, float* __restrict__ ws0) {
    int t = blockIdx.x * 256 + threadIdx.x;     // 65536 threads, float2 each
    float2 x = ((const float2*)v)[t];
    float s = x.x * x.x + x.y * x.y;
    #pragma unroll
    for (int m = 1; m < 64; m <<= 1) s += __shfl_xor(s, m);
    __shared__ float ls[4];
    int w = threadIdx.x >> 6;
    if ((threadIdx.x & 63) == 0) ls[w] = s;
    __syncthreads();
    if (threadIdx.x == 0) atomicAdd(ws0, ls[0] + ls[1] + ls[2] + ls[3]);
}

// ---------------- K2: W=g*v/||v|| -> bf16 ; efeat -> bf16 (skip masked rows) ----------------
__global__ void kconv(const float* __restrict__ v, const float* __restrict__ g,
                      const float* __restrict__ ef, const float* __restrict__ ws0,
                      const int* __restrict__ nen,
                      ushort_t* __restrict__ wsW, ushort_t* __restrict__ wsE) {
    int bid = blockIdx.x;
    if (bid < 128) {
        int t = bid * 256 + threadIdx.x;        // 32768 threads * 4 elems = 131072
        float s = g[0] * rsqrtf(ws0[0]);
        float4 x = ((const float4*)v)[t];
        short2 a = cvt2(x.x * s, x.y * s);
        short2 b = cvt2(x.z * s, x.w * s);
        ushort4 o;
        o.x = (ushort_t)a.x; o.y = (ushort_t)a.y; o.z = (ushort_t)b.x; o.w = (ushort_t)b.y;
        ((ushort4*)wsW)[t] = o;
    } else {
        long t = (long)(bid - 128) * 256 + threadIdx.x;  // float4 index into efeat
        int row = (int)(t >> 6);                 // 64 float4 per 256-col row
        int n = row & (NEN - 1);
        int b = row >> 10;
        if (n < nen[b]) {                        // rows >= ne are never read by kattn
            float4 x = ((const float4*)ef)[t];
            short2 a = cvt2(x.x, x.y);
            short2 c = cvt2(x.z, x.w);
            ushort4 o;
            o.x = (ushort_t)a.x; o.y = (ushort_t)a.y; o.z = (ushort_t)c.x; o.w = (ushort_t)c.y;
            ((ushort4*)wsE)[t] = o;
        }
    }
}

// ---------------- K3: proj = relu(ufeat @ W^T + b) -> bf16 ----------------
// block: 32 m-rows x all 256 n-cols. 4 waves, wave w owns n in [w*64, w*64+64).
__launch_bounds__(256, 2)
__global__ void kgemm1(const float* __restrict__ A, const ushort_t* __restrict__ W,
                       const float* __restrict__ bias, ushort_t* __restrict__ P) {
    const int tid = threadIdx.x;
    const int w = tid >> 6, L = tid & 63;
    const int rA = L & 15, q = L >> 4;
    const long mt = (long)blockIdx.x * 32;

    floatx4 acc[2][4];
    #pragma unroll
    for (int t = 0; t < 2; t++)
        #pragma unroll
        for (int n = 0; n < 4; n++) acc[t][n] = (floatx4){0.f, 0.f, 0.f, 0.f};

    const float* a0 = A + (mt + rA) * UF + q * 8;
    const float* a1 = A + (mt + 16 + rA) * UF + q * 8;
    const ushort_t* wp0 = W + (long)(w * 64 + 0 * 16 + rA) * UF + q * 8;
    const ushort_t* wp1 = W + (long)(w * 64 + 1 * 16 + rA) * UF + q * 8;
    const ushort_t* wp2 = W + (long)(w * 64 + 2 * 16 + rA) * UF + q * 8;
    const ushort_t* wp3 = W + (long)(w * 64 + 3 * 16 + rA) * UF + q * 8;

    #pragma unroll 2
    for (int s = 0; s < 16; s++) {
        const int ko = s * 32;
        float4 x0 = *(const float4*)(a0 + ko);
        float4 y0 = *(const float4*)(a0 + ko + 4);
        float4 x1 = *(const float4*)(a1 + ko);
        float4 y1 = *(const float4*)(a1 + ko + 4);
        short8 af0 = cvt8(x0, y0);
        short8 af1 = cvt8(x1, y1);
        short8 b0 = *(const short8*)(wp0 + ko);
        short8 b1 = *(const short8*)(wp1 + ko);
        short8 b2 = *(const short8*)(wp2 + ko);
        short8 b3 = *(const short8*)(wp3 + ko);
        acc[0][0] = __builtin_amdgcn_mfma_f32_16x16x32_bf16(af0, b0, acc[0][0], 0, 0, 0);
        acc[1][0] = __builtin_amdgcn_mfma_f32_16x16x32_bf16(af1, b0, acc[1][0], 0, 0, 0);
        acc[0][1] = __builtin_amdgcn_mfma_f32_16x16x32_bf16(af0, b1, acc[0][1], 0, 0, 0);
        acc[1][1] = __builtin_amdgcn_mfma_f32_16x16x32_bf16(af1, b1, acc[1][1], 0, 0, 0);
        acc[0][2] = __builtin_amdgcn_mfma_f32_16x16x32_bf16(af0, b2, acc[0][2], 0, 0, 0);
        acc[1][2] = __builtin_amdgcn_mfma_f32_16x16x32_bf16(af1, b2, acc[1][2], 0, 0, 0);
        acc[0][3] = __builtin_amdgcn_mfma_f32_16x16x32_bf16(af0, b3, acc[0][3], 0, 0, 0);
        acc[1][3] = __builtin_amdgcn_mfma_f32_16x16x32_bf16(af1, b3, acc[1][3], 0, 0, 0);
    }

    #pragma unroll
    for (int n = 0; n < 4; n++) {
        const int col = w * 64 + n * 16 + rA;
        const float bv = bias[col];
        #pragma unroll
        for (int t = 0; t < 2; t++) {
            #pragma unroll
            for (int i = 0; i < 4; i++) {
                float val = acc[t][n][i] + bv;
                val = fmaxf(val, 0.f);
                const long row = mt + t * 16 + q * 4 + i;
                P[row * EF + col] = f2bfbits(val);
            }
        }
    }
}

// ---------------- K4: logits -> (no-max) softmax -> prob ----------------
// block: one (b, ut16) pair; 16 u-rows x all 1024 n. wave w owns n in [w*256,(w+1)*256).
// Halved u-rows per block (vs 32) => acc[16]+af[8] ~ 96 VGPRs => 3 waves/SIMD.
// Wave-uniform skip of fully-masked 16-col steps (exp(-1e9-max) == 0 exactly in ref).
__launch_bounds__(256, 3)
__global__ void kattn(const ushort_t* __restrict__ P, const ushort_t* __restrict__ E,
                      const int* __restrict__ nen, float* __restrict__ out) {
    const int tid = threadIdx.x;
    const int w = tid >> 6, L = tid & 63;
    const int rA = L & 15, q = L >> 4;
    const int bid = blockIdx.x;
    // b-sequential XCD swizzle: each XCD owns 8 b's and walks all 64 ut-blocks of a b
    // before advancing => per-XCD L2 working set ~1 b (E 512KB + P 512KB) << 4MB.
    const int xcd = bid & 7;
    const int idx = bid >> 3;            // 0..511
    const int b = xcd * 8 + (idx >> 6);  // 0..63
    const int ut = idx & 63;             // 0..63, 16 u-rows each
    const int ne = nen[b];

    // Preload A-frags (proj tile 16x256) once; reused across all n-steps.
    const ushort_t* prow = P + (long)(b * NU + ut * 16 + rA) * EF + q * 8;
    short8 af[8];
    #pragma unroll
    for (int s = 0; s < 8; s++) af[s] = *(const short8*)(prow + s * 32);

    floatx4 acc[16];
    #pragma unroll
    for (int ns = 0; ns < 16; ns++) acc[ns] = (floatx4){0.f, 0.f, 0.f, 0.f};
    float psum[4] = {0.f, 0.f, 0.f, 0.f};

    const ushort_t* erow = E + (long)(b * NEN + w * 256 + rA) * EF + q * 8;

    #pragma unroll
    for (int ns = 0; ns < 16; ns++) {
        const int col0 = w * 256 + ns * 16;
        if (col0 < ne) {                 // wave-uniform: skip fully-masked steps
            const ushort_t* ep = erow + (long)ns * 16 * EF;
            floatx4 c = (floatx4){0.f, 0.f, 0.f, 0.f};
            #pragma unroll
            for (int h = 0; h < 2; h++) {
                short8 bf[4];
                #pragma unroll
                for (int s = 0; s < 4; s++) bf[s] = *(const short8*)(ep + (h * 4 + s) * 32);
                #pragma unroll
                for (int s = 0; s < 4; s++)
                    c = __builtin_amdgcn_mfma_f32_16x16x32_bf16(af[h * 4 + s], bf[s], c, 0, 0, 0);
            }
            const int col = col0 + rA;
            const bool on = col < ne;    // boundary lanes: garbage E rows masked off
            #pragma unroll
            for (int i = 0; i < 4; i++) {
                float e = on ? __expf(c[i] * 0.0625f) : 0.f;
                c[i] = e;
                psum[i] += e;
            }
            acc[ns] = c;
        }
    }

    // Row sums: reduce over the 16 lanes sharing q (cols), then across waves via LDS.
    #pragma unroll
    for (int i = 0; i < 4; i++) {
        float s = psum[i];
        s += __shfl_xor(s, 1);
        s += __shfl_xor(s, 2);
        s += __shfl_xor(s, 4);
        s += __shfl_xor(s, 8);
        psum[i] = s;
    }
    __shared__ float lsum[4][16];
    if (rA == 0) {
        #pragma unroll
        for (int i = 0; i < 4; i++) lsum[w][q * 4 + i] = psum[i];
    }
    __syncthreads();

    float inv[4];
    #pragma unroll
    for (int i = 0; i < 4; i++) {
        const int r = q * 4 + i;
        const float tot = lsum[0][r] + lsum[1][r] + lsum[2][r] + lsum[3][r];
        inv[i] = (ne > 0) ? (1.f / tot) : 0.f;
    }

    const float uni = 1.f / 1024.f;
    float* orow = out + ((long)(b * NU + ut * 16)) * (long)NEN + w * 256;
    #pragma unroll
    for (int ns = 0; ns < 16; ns++) {
        #pragma unroll
        for (int i = 0; i < 4; i++) {
            const int u = q * 4 + i;
            const float val = (ne == 0) ? uni : acc[ns][i] * inv[i];
            orow[(long)u * NEN + ns * 16 + rA] = val;
        }
    }
}

extern "C" void kernel_launch(void* const* d_in, const int* in_sizes, int n_in,
                              void* d_out, int out_size, void* d_ws, size_t ws_size,
                              hipStream_t stream) {
    (void)in_sizes; (void)n_in; (void)out_size; (void)ws_size;
    const float* ufeat = (const float*)d_in[0];
    const float* efeat = (const float*)d_in[1];
    const int*   nen   = (const int*)d_in[2];
    const float* v     = (const float*)d_in[3];
    const float* g     = (const float*)d_in[4];
    const float* bias  = (const float*)d_in[5];
    float* out = (float*)d_out;

    float*    ws0 = (float*)d_ws;
    ushort_t* wsW = (ushort_t*)((char*)d_ws + 1024);                       // 256 KB
    ushort_t* wsE = (ushort_t*)((char*)d_ws + (1u << 20));                 // 32 MB
    ushort_t* wsP = (ushort_t*)((char*)d_ws + (1u << 20) + (32u << 20));   // 32 MB

    hipMemsetAsync(d_ws, 0, 256, stream);
    knorm<<<256, 256, 0, stream>>>(v, ws0);
    kconv<<<16512, 256, 0, stream>>>(v, g, efeat, ws0, nen, wsW, wsE);
    kgemm1<<<2048, 256, 0, stream>>>(ufeat, wsW, bias, wsP);
    kattn<<<4096, 256, 0, stream>>>(wsP, wsE, nen, out);
}

// Round 3
// 594.104 us; speedup vs baseline: 1.0980x; 1.0980x over previous
//
#include <hip/hip_runtime.h>
#include <hip/hip_bf16.h>

#define UF 512
#define EF 256
#define NB 64
#define NU 1024
#define NEN 1024

typedef __attribute__((ext_vector_type(8))) short short8;   // 8 bf16 (4 VGPRs)
typedef __attribute__((ext_vector_type(4))) float floatx4;  // MFMA acc / ext-vector f32x4

typedef unsigned short ushort_t;

__device__ inline short2 cvt2(float a, float b) {
    __hip_bfloat162 h = __float22bfloat162_rn(make_float2(a, b));
    union { __hip_bfloat162 h; short2 s; } u;
    u.h = h;
    return u.s;
}

__device__ inline short8 cvt8v(floatx4 x, floatx4 y) {
    union { short8 v; short2 s[4]; } u;
    u.s[0] = cvt2(x[0], x[1]);
    u.s[1] = cvt2(x[2], x[3]);
    u.s[2] = cvt2(y[0], y[1]);
    u.s[3] = cvt2(y[2], y[3]);
    return u.v;
}

__device__ inline ushort_t f2bfbits(float f) {
    unsigned u = __float_as_uint(f);
    u += 0x7FFFu + ((u >> 16) & 1u);   // round-to-nearest-even
    return (ushort_t)(u >> 16);
}

// ---------------- K1: ||v||^2 ----------------
__global__ void knorm(const float* __restrict__ v, float* __restrict__ ws0) {
    int t = blockIdx.x * 256 + threadIdx.x;     // 65536 threads, float2 each
    float2 x = ((const float2*)v)[t];
    float s = x.x * x.x + x.y * x.y;
    #pragma unroll
    for (int m = 1; m < 64; m <<= 1) s += __shfl_xor(s, m);
    __shared__ float ls[4];
    int w = threadIdx.x >> 6;
    if ((threadIdx.x & 63) == 0) ls[w] = s;
    __syncthreads();
    if (threadIdx.x == 0) atomicAdd(ws0, ls[0] + ls[1] + ls[2] + ls[3]);
}

// ---------------- K2: W=g*v/||v|| -> bf16 ; efeat -> bf16 (skip masked rows) ----------------
__global__ void kconv(const float* __restrict__ v, const float* __restrict__ g,
                      const float* __restrict__ ef, const float* __restrict__ ws0,
                      const int* __restrict__ nen,
                      ushort_t* __restrict__ wsW, ushort_t* __restrict__ wsE) {
    int bid = blockIdx.x;
    if (bid < 128) {
        int t = bid * 256 + threadIdx.x;        // 32768 threads * 4 elems = 131072
        float s = g[0] * rsqrtf(ws0[0]);
        float4 x = ((const float4*)v)[t];
        short2 a = cvt2(x.x * s, x.y * s);
        short2 b = cvt2(x.z * s, x.w * s);
        ushort4 o;
        o.x = (ushort_t)a.x; o.y = (ushort_t)a.y; o.z = (ushort_t)b.x; o.w = (ushort_t)b.y;
        ((ushort4*)wsW)[t] = o;
    } else {
        long t = (long)(bid - 128) * 256 + threadIdx.x;  // float4 index into efeat
        int row = (int)(t >> 6);                 // 64 float4 per 256-col row
        int n = row & (NEN - 1);
        int b = row >> 10;
        if (n < nen[b]) {                        // rows >= ne are never read by kattn
            float4 x = ((const float4*)ef)[t];
            short2 a = cvt2(x.x, x.y);
            short2 c = cvt2(x.z, x.w);
            ushort4 o;
            o.x = (ushort_t)a.x; o.y = (ushort_t)a.y; o.z = (ushort_t)c.x; o.w = (ushort_t)c.y;
            ((ushort4*)wsE)[t] = o;
        }
    }
}

// ---------------- K3: proj = relu(ufeat @ W^T + b) -> bf16 ----------------
// block: 64 m-rows x all 256 n-cols. 4 waves; wave w owns n in [w*64, w*64+64).
// 16 independent MFMAs per k-step; halves W re-fetch from L2 vs 32-row blocks.
__launch_bounds__(256, 2)
__global__ void kgemm1(const float* __restrict__ A, const ushort_t* __restrict__ W,
                       const float* __restrict__ bias, ushort_t* __restrict__ P) {
    const int tid = threadIdx.x;
    const int w = tid >> 6, L = tid & 63;
    const int rA = L & 15, q = L >> 4;
    const long mt = (long)blockIdx.x * 64;

    floatx4 acc[4][4];
    #pragma unroll
    for (int m = 0; m < 4; m++)
        #pragma unroll
        for (int n = 0; n < 4; n++) acc[m][n] = (floatx4){0.f, 0.f, 0.f, 0.f};

    const float* ap[4];
    const ushort_t* wp[4];
    #pragma unroll
    for (int m = 0; m < 4; m++) ap[m] = A + (mt + m * 16 + rA) * UF + q * 8;
    #pragma unroll
    for (int n = 0; n < 4; n++) wp[n] = W + (long)(w * 64 + n * 16 + rA) * UF + q * 8;

    #pragma unroll 2
    for (int s = 0; s < 16; s++) {
        const int ko = s * 32;
        short8 af[4];
        #pragma unroll
        for (int m = 0; m < 4; m++) {
            floatx4 x = __builtin_nontemporal_load((const floatx4*)(ap[m] + ko));
            floatx4 y = __builtin_nontemporal_load((const floatx4*)(ap[m] + ko + 4));
            af[m] = cvt8v(x, y);
        }
        short8 bfr[4];
        #pragma unroll
        for (int n = 0; n < 4; n++) bfr[n] = *(const short8*)(wp[n] + ko);
        #pragma unroll
        for (int n = 0; n < 4; n++)
            #pragma unroll
            for (int m = 0; m < 4; m++)
                acc[m][n] = __builtin_amdgcn_mfma_f32_16x16x32_bf16(af[m], bfr[n], acc[m][n], 0, 0, 0);
    }

    #pragma unroll
    for (int n = 0; n < 4; n++) {
        const int col = w * 64 + n * 16 + rA;
        const float bv = bias[col];
        #pragma unroll
        for (int m = 0; m < 4; m++) {
            #pragma unroll
            for (int i = 0; i < 4; i++) {
                float val = acc[m][n][i] + bv;
                val = fmaxf(val, 0.f);
                const long row = mt + m * 16 + q * 4 + i;
                P[row * EF + col] = f2bfbits(val);
            }
        }
    }
}

// ---------------- K4: logits -> (no-max) softmax -> prob ----------------
// block: one (b, ut32) pair; 32 u-rows x all 1024 n.
// Wave w owns INTERLEAVED 16-col steps: col0 = ns*64 + w*16 (ns=0..15), so the
// masked-column skip is load-balanced across waves (max spread: 1 step).
// Two independent MFMA chains (t=0,1) per step for ILP.
// b-major block order: all XCDs walk the same 1-2 b's at a time -> L2 locality
// without static per-XCD b assignment (which can't be ne-balanced).
__launch_bounds__(256, 2)
__global__ void kattn(const ushort_t* __restrict__ P, const ushort_t* __restrict__ E,
                      const int* __restrict__ nen, float* __restrict__ out) {
    const int tid = threadIdx.x;
    const int w = tid >> 6, L = tid & 63;
    const int rA = L & 15, q = L >> 4;
    const int bid = blockIdx.x;
    const int b = bid >> 5;              // b-major
    const int ut = bid & 31;             // 0..31, 32 u-rows each
    const int ne = nen[b];

    // Preload A-frags (proj tile 32x256) once; reused across all active n-steps.
    const ushort_t* prow = P + (long)(b * NU + ut * 32 + rA) * EF + q * 8;
    short8 af[2][8];
    #pragma unroll
    for (int t = 0; t < 2; t++)
        #pragma unroll
        for (int s = 0; s < 8; s++)
            af[t][s] = *(const short8*)(prow + t * 16 * EF + s * 32);

    floatx4 acc[2][16];
    #pragma unroll
    for (int t = 0; t < 2; t++)
        #pragma unroll
        for (int ns = 0; ns < 16; ns++) acc[t][ns] = (floatx4){0.f, 0.f, 0.f, 0.f};
    float psum[2][4];
    #pragma unroll
    for (int t = 0; t < 2; t++)
        #pragma unroll
        for (int i = 0; i < 4; i++) psum[t][i] = 0.f;

    // E rows for this wave's steps: row = ns*64 + w*16 + rA
    const ushort_t* erow = E + (long)(b * NEN + w * 16 + rA) * EF + q * 8;

    #pragma unroll
    for (int ns = 0; ns < 16; ns++) {
        const int col0 = ns * 64 + w * 16;
        if (col0 < ne) {                 // wave-uniform skip, balanced across waves
            const ushort_t* ep = erow + (long)ns * 64 * EF;
            floatx4 c0 = (floatx4){0.f, 0.f, 0.f, 0.f};
            floatx4 c1 = (floatx4){0.f, 0.f, 0.f, 0.f};
            #pragma unroll
            for (int h = 0; h < 2; h++) {
                short8 bf[4];
                #pragma unroll
                for (int s = 0; s < 4; s++) bf[s] = *(const short8*)(ep + (h * 4 + s) * 32);
                #pragma unroll
                for (int s = 0; s < 4; s++) {
                    c0 = __builtin_amdgcn_mfma_f32_16x16x32_bf16(af[0][h * 4 + s], bf[s], c0, 0, 0, 0);
                    c1 = __builtin_amdgcn_mfma_f32_16x16x32_bf16(af[1][h * 4 + s], bf[s], c1, 0, 0, 0);
                }
            }
            const int col = col0 + rA;
            const bool on = col < ne;    // boundary lanes: garbage E rows masked off
            #pragma unroll
            for (int i = 0; i < 4; i++) {
                float e0 = on ? __expf(c0[i] * 0.0625f) : 0.f;
                float e1 = on ? __expf(c1[i] * 0.0625f) : 0.f;
                c0[i] = e0; c1[i] = e1;
                psum[0][i] += e0; psum[1][i] += e1;
            }
            acc[0][ns] = c0;
            acc[1][ns] = c1;
        }
    }

    // Row sums: reduce over the 16 lanes sharing q (cols), then across waves via LDS.
    #pragma unroll
    for (int t = 0; t < 2; t++)
        #pragma unroll
        for (int i = 0; i < 4; i++) {
            float s = psum[t][i];
            s += __shfl_xor(s, 1);
            s += __shfl_xor(s, 2);
            s += __shfl_xor(s, 4);
            s += __shfl_xor(s, 8);
            psum[t][i] = s;
        }
    __shared__ float lsum[4][32];
    if (rA == 0) {
        #pragma unroll
        for (int t = 0; t < 2; t++)
            #pragma unroll
            for (int i = 0; i < 4; i++)
                lsum[w][t * 16 + q * 4 + i] = psum[t][i];
    }
    __syncthreads();

    float inv[2][4];
    #pragma unroll
    for (int t = 0; t < 2; t++)
        #pragma unroll
        for (int i = 0; i < 4; i++) {
            const int r = t * 16 + q * 4 + i;
            const float tot = lsum[0][r] + lsum[1][r] + lsum[2][r] + lsum[3][r];
            inv[t][i] = (ne > 0) ? (1.f / tot) : 0.f;
        }

    const float uni = 1.f / 1024.f;
    // out is never re-read: nontemporal stores keep the 263MB stream out of L2.
    float* orow = out + ((long)(b * NU + ut * 32)) * (long)NEN + w * 16;
    #pragma unroll
    for (int ns = 0; ns < 16; ns++) {
        #pragma unroll
        for (int t = 0; t < 2; t++) {
            #pragma unroll
            for (int i = 0; i < 4; i++) {
                const int u = t * 16 + q * 4 + i;
                const float val = (ne == 0) ? uni : acc[t][ns][i] * inv[t][i];
                __builtin_nontemporal_store(val, &orow[(long)u * NEN + ns * 64 + rA]);
            }
        }
    }
}

extern "C" void kernel_launch(void* const* d_in, const int* in_sizes, int n_in,
                              void* d_out, int out_size, void* d_ws, size_t ws_size,
                              hipStream_t stream) {
    (void)in_sizes; (void)n_in; (void)out_size; (void)ws_size;
    const float* ufeat = (const float*)d_in[0];
    const float* efeat = (const float*)d_in[1];
    const int*   nen   = (const int*)d_in[2];
    const float* v     = (const float*)d_in[3];
    const float* g     = (const float*)d_in[4];
    const float* bias  = (const float*)d_in[5];
    float* out = (float*)d_out;

    float*    ws0 = (float*)d_ws;
    ushort_t* wsW = (ushort_t*)((char*)d_ws + 1024);                       // 256 KB
    ushort_t* wsE = (ushort_t*)((char*)d_ws + (1u << 20));                 // 32 MB
    ushort_t* wsP = (ushort_t*)((char*)d_ws + (1u << 20) + (32u << 20));   // 32 MB

    hipMemsetAsync(d_ws, 0, 256, stream);
    knorm<<<256, 256, 0, stream>>>(v, ws0);
    kconv<<<16512, 256, 0, stream>>>(v, g, efeat, ws0, nen, wsW, wsE);
    kgemm1<<<1024, 256, 0, stream>>>(ufeat, wsW, bias, wsP);
    kattn<<<2048, 256, 0, stream>>>(wsP, wsE, nen, out);
}